// Round 2
// baseline (1649.557 us; speedup 1.0000x reference)
//
#include <hip/hip_runtime.h>
#include <math.h>

#define NEGV -1e32f

typedef __bf16 bf16_t;
typedef __bf16 bf16x8 __attribute__((ext_vector_type(8)));
typedef __bf16 bf16x4 __attribute__((ext_vector_type(4)));
typedef float floatx4 __attribute__((ext_vector_type(4)));

// ---------------- wave helpers ----------------
static __device__ __forceinline__ float wave_sum(float v) {
#pragma unroll
  for (int d = 32; d > 0; d >>= 1) v += __shfl_xor(v, d, 64);
  return v;
}
static __device__ __forceinline__ float wave_max(float v) {
#pragma unroll
  for (int d = 32; d > 0; d >>= 1) v = fmaxf(v, __shfl_xor(v, d, 64));
  return v;
}

// async global->LDS, 16B per lane; LDS dest is wave-uniform base + lane*16
static __device__ __forceinline__ void gl2lds16(const bf16_t* g, bf16_t* l) {
  __builtin_amdgcn_global_load_lds((__attribute__((address_space(1))) void*)(void*)g,
                                   (__attribute__((address_space(3))) void*)l, 16, 0, 0);
}

// ---------------- GEMM: C[m,n] = alpha * sum_k A[m,k]*B[n,k] (+bias) ----------------
// A,B bf16 K-contiguous. 128x128 tile, BK=32, 256 threads (4 waves, 2x2 of 64x64).
// Batch z: operand offset = (z/zdiv)*so + (z%zdiv)*si  (element units).
// BIAS_MODE: 0 none, 1 per-col(n), 2 per-row(m).
template <int BIAS_MODE, bool RELU, bool OUT_BF16>
__global__ __launch_bounds__(256) void gemm_bt(
    const bf16_t* __restrict__ A, long lda, long a_so, long a_si,
    const bf16_t* __restrict__ B, long ldb, long b_so, long b_si,
    void* __restrict__ Cv, long ldc, long c_so, long c_si,
    const float* __restrict__ bias, int zdiv, int K, float alpha)
{
  __shared__ bf16_t As[4096];  // 128 rows x 32 (bf16)
  __shared__ bf16_t Bs[4096];
  const int tid = threadIdx.x;
  const int wave = tid >> 6;
  const int lane = tid & 63;
  const int wr = wave >> 1;
  const int wc = wave & 1;
  const int z = blockIdx.z;
  const long zo = z / zdiv;
  const long zi = z % zdiv;
  A += zo * a_so + zi * a_si;
  B += zo * b_so + zi * b_si;
  const long m0 = (long)blockIdx.x * 128;
  const long n0 = (long)blockIdx.y * 128;

  // staging: chunk id = tid ; row = id>>2 ; 16B col group = (id&3)*8
  const int srow = tid >> 2;
  const int scol = (tid & 3) * 8;
  const bf16_t* gA0 = A + (m0 + srow) * lda + scol;
  const bf16_t* gA1 = A + (m0 + srow + 64) * lda + scol;
  const bf16_t* gB0 = B + (n0 + srow) * ldb + scol;
  const bf16_t* gB1 = B + (n0 + srow + 64) * ldb + scol;
  bf16_t* lA0 = As + wave * 512;          // uniform per-wave base (lane*16B added by HW)
  bf16_t* lA1 = As + 2048 + wave * 512;
  bf16_t* lB0 = Bs + wave * 512;
  bf16_t* lB1 = Bs + 2048 + wave * 512;

  floatx4 acc[4][4] = {};
  const int lr = lane & 15;
  const int kof = (lane >> 4) * 8;

  for (int k0 = 0; k0 < K; k0 += 32) {
    gl2lds16(gA0 + k0, lA0);
    gl2lds16(gA1 + k0, lA1);
    gl2lds16(gB0 + k0, lB0);
    gl2lds16(gB1 + k0, lB1);
    __syncthreads();
    bf16x8 af[4], bfr[4];
#pragma unroll
    for (int t = 0; t < 4; ++t) {
      af[t]  = *(const bf16x8*)(As + (wr * 64 + t * 16 + lr) * 32 + kof);
      bfr[t] = *(const bf16x8*)(Bs + (wc * 64 + t * 16 + lr) * 32 + kof);
    }
#pragma unroll
    for (int tm = 0; tm < 4; ++tm)
#pragma unroll
      for (int tn = 0; tn < 4; ++tn)
        acc[tm][tn] = __builtin_amdgcn_mfma_f32_16x16x32_bf16(af[tm], bfr[tn], acc[tm][tn], 0, 0, 0);
    __syncthreads();
  }

  // epilogue: C/D layout col=lane&15, row=(lane>>4)*4+reg (m89-verified)
  const long coff = zo * c_so + zi * c_si;
  const int q4 = (lane >> 4) * 4;
#pragma unroll
  for (int tm = 0; tm < 4; ++tm) {
#pragma unroll
    for (int tn = 0; tn < 4; ++tn) {
#pragma unroll
      for (int r = 0; r < 4; ++r) {
        const long row = m0 + wr * 64 + tm * 16 + q4 + r;
        const long col = n0 + wc * 64 + tn * 16 + lr;
        float v = acc[tm][tn][r] * alpha;
        if (BIAS_MODE == 1) v += bias[col];
        if (BIAS_MODE == 2) v += bias[row];
        if (RELU) v = fmaxf(v, 0.0f);
        const long idx = coff + row * ldc + col;
        if (OUT_BF16) ((bf16_t*)Cv)[idx] = (bf16_t)v;
        else          ((float*)Cv)[idx]  = v;
      }
    }
  }
}

// ---------------- fp32 -> bf16 cast ----------------
__global__ __launch_bounds__(256) void cast_kernel(const float* __restrict__ in,
                                                   bf16_t* __restrict__ out, long n)
{
  const long i = ((long)blockIdx.x * 256 + threadIdx.x) * 4;
  if (i >= n) return;
  const float4 v = *(const float4*)(in + i);
  bf16x4 o;
  o[0] = (bf16_t)v.x; o[1] = (bf16_t)v.y; o[2] = (bf16_t)v.z; o[3] = (bf16_t)v.w;
  *(bf16x4*)(out + i) = o;
}

// ---------------- gumbel choice bits: b[l,h,s] = (logit0 >= logit1) ----------------
__global__ void bbit_kernel(const float* __restrict__ alphas, const float* __restrict__ E,
                            int* __restrict__ bbit, int n)
{
  const int i = blockIdx.x * 256 + threadIdx.x;
  if (i >= n) return;
  const float l0 = alphas[2 * i]     - logf(E[2 * i]     + 1e-5f);
  const float l1 = alphas[2 * i + 1] - logf(E[2 * i + 1] + 1e-5f);
  bbit[i] = (l0 >= l1) ? 1 : 0;
}

// ---------------- LayerNorm(X + R) * g + b ; one block per 1024-row ----------------
// X (residual) is fp32 or bf16 depending on XBF; R is fp32. out32/out16 nullable.
template <bool XBF>
__global__ __launch_bounds__(256) void ln_kernel(
    const void* __restrict__ Xv, const float* __restrict__ R,
    const float* __restrict__ g, const float* __restrict__ b,
    float* __restrict__ out32, bf16_t* __restrict__ out16)
{
  const long row = blockIdx.x;
  const int t = threadIdx.x;
  float x0, x1, x2, x3;
  if (XBF) {
    const bf16x4 xv = *(const bf16x4*)((const bf16_t*)Xv + row * 1024 + t * 4);
    x0 = (float)xv[0]; x1 = (float)xv[1]; x2 = (float)xv[2]; x3 = (float)xv[3];
  } else {
    const float4 xv = *(const float4*)((const float*)Xv + row * 1024 + t * 4);
    x0 = xv.x; x1 = xv.y; x2 = xv.z; x3 = xv.w;
  }
  const float4 rv = *(const float4*)(R + row * 1024 + t * 4);
  const float v0 = x0 + rv.x, v1 = x1 + rv.y, v2 = x2 + rv.z, v3 = x3 + rv.w;
  float s  = v0 + v1 + v2 + v3;
  float s2 = v0 * v0 + v1 * v1 + v2 * v2 + v3 * v3;
  s = wave_sum(s); s2 = wave_sum(s2);
  __shared__ float red[8];
  const int wv = t >> 6, lane = t & 63;
  if (lane == 0) { red[wv] = s; red[4 + wv] = s2; }
  __syncthreads();
  s  = red[0] + red[1] + red[2] + red[3];
  s2 = red[4] + red[5] + red[6] + red[7];
  const float mu = s * (1.0f / 1024.0f);
  const float var = s2 * (1.0f / 1024.0f) - mu * mu;
  const float rstd = rsqrtf(var + 1e-5f);
  const float4 gv = *(const float4*)(g + t * 4);
  const float4 bv = *(const float4*)(b + t * 4);
  float4 ov;
  ov.x = (v0 - mu) * rstd * gv.x + bv.x;
  ov.y = (v1 - mu) * rstd * gv.y + bv.y;
  ov.z = (v2 - mu) * rstd * gv.z + bv.z;
  ov.w = (v3 - mu) * rstd * gv.w + bv.w;
  if (out32) *(float4*)(out32 + row * 1024 + t * 4) = ov;
  if (out16) {
    bf16x4 oh;
    oh[0] = (bf16_t)ov.x; oh[1] = (bf16_t)ov.y; oh[2] = (bf16_t)ov.z; oh[3] = (bf16_t)ov.w;
    *(bf16x4*)(out16 + row * 1024 + t * 4) = oh;
  }
}

// ---------------- attention mid: per row of S (512), one wave per row ----------------
// dam[h,i,j] = (j<i+bmask) || b[h,j-i]==0 ; band = j<i+bmask
// p = softmax(dam? s : NEG); sc = band? p : 0; c = cumsum(sc); tot = sum(sc)
// te = clip(exp(sqrt(max((tot-c)*|i-j|,0)) * (-softplus(gamma_h))), 1e-5, 1e5)
// P = softmax(band? s*te : NEG); zero_pad zeroes row i==0.
__global__ __launch_bounds__(256) void attn_mid(
    const float* __restrict__ S, bf16_t* __restrict__ P,
    const int* __restrict__ bbit, const float* __restrict__ gam,
    const int bmask, const int zero_pad, const int bh0)
{
  const int wid = threadIdx.x >> 6;
  const int lane = threadIdx.x & 63;
  const long rowid = (long)blockIdx.x * 4 + wid;
  const int i = (int)(rowid & 511);
  const int bh_local = (int)(rowid >> 9);
  const int h = (bh0 + bh_local) & 7;
  const float* s = S + rowid * 512;
  const int jb = lane * 8;

  const float gv = gam[h];
  const float gamma = -log1pf(expf(gv));  // -softplus

  float sv[8];
  {
    const float4 a = *(const float4*)(s + jb);
    const float4 b = *(const float4*)(s + jb + 4);
    sv[0] = a.x; sv[1] = a.y; sv[2] = a.z; sv[3] = a.w;
    sv[4] = b.x; sv[5] = b.y; sv[6] = b.z; sv[7] = b.w;
  }
  const int* bb = bbit + h * 512;
  float z[8];
  bool band[8];
  float m1 = NEGV;
#pragma unroll
  for (int u = 0; u < 8; ++u) {
    const int j = jb + u;
    const bool bd = j < i + bmask;
    band[u] = bd;
    int d = j - i; d = d < 0 ? 0 : d;
    const bool allowed = bd || (bb[d] == 0);
    z[u] = allowed ? sv[u] : NEGV;
    m1 = fmaxf(m1, z[u]);
  }
  m1 = wave_max(m1);
  float e[8], es = 0.f;
#pragma unroll
  for (int u = 0; u < 8; ++u) { e[u] = expf(z[u] - m1); es += e[u]; }
  es = wave_sum(es);
  const float inv1 = 1.0f / es;

  float c[8];
  float run = 0.f;
#pragma unroll
  for (int u = 0; u < 8; ++u) {
    const float p = band[u] ? e[u] * inv1 : 0.f;
    run += p;
    c[u] = run;
  }
  float x = run;
#pragma unroll
  for (int d = 1; d < 64; d <<= 1) {
    const float y = __shfl_up(x, (unsigned)d, 64);
    if (lane >= d) x += y;
  }
  const float tot = __shfl(x, 63, 64);
  const float ex = x - run;  // exclusive prefix across lanes

  float z2[8];
  float m2 = NEGV;
#pragma unroll
  for (int u = 0; u < 8; ++u) {
    const int j = jb + u;
    const float cc = c[u] + ex;
    const float pos = fabsf((float)(i - j));
    const float dist = sqrtf(fmaxf((tot - cc) * pos, 0.f));
    float te = expf(dist * gamma);
    te = fminf(fmaxf(te, 1e-5f), 1e5f);
    z2[u] = band[u] ? sv[u] * te : NEGV;
    m2 = fmaxf(m2, z2[u]);
  }
  m2 = wave_max(m2);
  float f[8], es2 = 0.f;
#pragma unroll
  for (int u = 0; u < 8; ++u) { f[u] = expf(z2[u] - m2); es2 += f[u]; }
  es2 = wave_sum(es2);
  const float inv2 = (zero_pad && i == 0) ? 0.f : (1.0f / es2);
  bf16x8 o;
#pragma unroll
  for (int u = 0; u < 8; ++u) o[u] = (bf16_t)(f[u] * inv2);
  *(bf16x8*)(P + rowid * 512 + jb) = o;
}

// ---------------- host ----------------
extern "C" void kernel_launch(void* const* d_in, const int* in_sizes, int n_in,
                              void* d_out, int out_size, void* d_ws, size_t ws_size,
                              hipStream_t stream)
{
  (void)in_sizes; (void)n_in; (void)out_size; (void)ws_size;
  const float* q_emb  = (const float*)d_in[0];
  const float* qa_emb = (const float*)d_in[1];
  const float* kW = (const float*)d_in[2];
  const float* kb = (const float*)d_in[3];
  const float* vW = (const float*)d_in[4];
  const float* vb = (const float*)d_in[5];
  const float* oW = (const float*)d_in[6];
  const float* ob = (const float*)d_in[7];
  const float* gammas = (const float*)d_in[8];
  const float* alphas = (const float*)d_in[9];
  const float* ln1_g = (const float*)d_in[10];
  const float* ln1_b = (const float*)d_in[11];
  const float* w1 = (const float*)d_in[12];
  const float* b1 = (const float*)d_in[13];
  const float* w2 = (const float*)d_in[14];
  const float* b2 = (const float*)d_in[15];
  const float* ln2_g = (const float*)d_in[16];
  const float* ln2_b = (const float*)d_in[17];
  const float* gumE = (const float*)d_in[18];
  float* outp = (float*)d_out;

  // ---- workspace layout: 200 MB total, phase-lifetime overlay ----
  // persistent: bbit@0(48K), VB@1M(16M), XB@17M(16M)
  // per-layer weights: kWb@33M(2M) vWb@35M(2M) oWb@37M(2M) w1b@39M(8M) w2b@47M(8M)
  // scratch overlay @56M..200M:
  //   phase A/B: KQB@56(16) VT@72(16) SS@88(32) PP@120(16) ATT@136(16)
  //   phase C:   O32@168(32)           (reads ATT@136)
  //   phase D:   X1@56(32) X1B@88(16)  (KQB/VT/SS dead)
  //   phase E/F: H1B@104(64)           (PP/ATT dead; O32@168 disjoint)
  const size_t MBc = 1ull << 20;
  char* W = (char*)d_ws;
  int*    bbit = (int*)W;
  bf16_t* VB   = (bf16_t*)(W + 1 * MBc);
  bf16_t* XB   = (bf16_t*)(W + 17 * MBc);
  bf16_t* kWb  = (bf16_t*)(W + 33 * MBc);
  bf16_t* vWb  = (bf16_t*)(W + 35 * MBc);
  bf16_t* oWb  = (bf16_t*)(W + 37 * MBc);
  bf16_t* w1b  = (bf16_t*)(W + 39 * MBc);
  bf16_t* w2b  = (bf16_t*)(W + 47 * MBc);
  bf16_t* KQB  = (bf16_t*)(W + 56 * MBc);
  bf16_t* VT   = (bf16_t*)(W + 72 * MBc);
  float*  SS   = (float*)(W + 88 * MBc);
  bf16_t* PP   = (bf16_t*)(W + 120 * MBc);
  bf16_t* ATT  = (bf16_t*)(W + 136 * MBc);
  float*  O32  = (float*)(W + 168 * MBc);
  float*  X1   = (float*)(W + 56 * MBc);
  bf16_t* X1B  = (bf16_t*)(W + 88 * MBc);
  bf16_t* H1B  = (bf16_t*)(W + 104 * MBc);

  const long ND = 8388608;  // B*S*D

  auto run_layer = [&](int l, const void* Qin, bool qin_bf16, const bf16_t* XBp,
                       const bf16_t* VBp, bool apply_pos, int bmask,
                       float* o32, bf16_t* o16) {
    // per-layer weight casts into fixed bf16 buffers
    cast_kernel<<<dim3(1024), dim3(256), 0, stream>>>(kW + (long)l * 1048576, kWb, 1048576);
    cast_kernel<<<dim3(1024), dim3(256), 0, stream>>>(vW + (long)l * 1048576, vWb, 1048576);
    cast_kernel<<<dim3(1024), dim3(256), 0, stream>>>(oW + (long)l * 1048576, oWb, 1048576);
    cast_kernel<<<dim3(4096), dim3(256), 0, stream>>>(w1 + (long)l * 4194304, w1b, 4194304);
    cast_kernel<<<dim3(4096), dim3(256), 0, stream>>>(w2 + (long)l * 4194304, w2b, 4194304);

    // q==k projection: (8192x1024)x(1024x1024)^T + kb -> KQB bf16
    gemm_bt<1, false, true><<<dim3(64, 8, 1), dim3(256), 0, stream>>>(
        XBp, 1024, 0, 0, kWb, 1024, 0, 0, (void*)KQB, 1024, 0, 0,
        kb + l * 1024, 1, 1024, 1.0f);
    // V^T projection: per batch b, C[d,s] = sum_k vW[d,k]*X[s,k] + vb[d]
    gemm_bt<2, false, true><<<dim3(8, 4, 16), dim3(256), 0, stream>>>(
        vWb, 1024, 0, 0, VBp, 1024, 524288, 0, (void*)VT, 512, 524288, 0,
        vb + l * 1024, 1, 1024, 1.0f);
    const int zp = (bmask == 0) ? 1 : 0;
    for (int c = 0; c < 4; ++c) {  // 32 (b,h) pairs per chunk = 4 full batches
      const bf16_t* kqc = KQB + (long)c * 4 * 524288;
      // S = Q K^T / sqrt(128)   (z: /8 -> b stride, %8 -> h stride)
      gemm_bt<0, false, false><<<dim3(4, 4, 32), dim3(256), 0, stream>>>(
          kqc, 1024, 524288, 128, kqc, 1024, 524288, 128,
          (void*)SS, 512, 2097152, 262144, nullptr, 8, 128, 0.08838834764831845f);
      attn_mid<<<dim3(4096), dim3(256), 0, stream>>>(
          SS, PP, bbit + l * 4096, gammas + l * 8, bmask, zp, c * 32);
      // att = P V : A=P (512x512), B=V^T (128x512), C->(B,S,H*DK) bf16
      gemm_bt<0, false, true><<<dim3(4, 1, 32), dim3(256), 0, stream>>>(
          PP, 512, 2097152, 262144, VT + (long)c * 4 * 524288, 512, 524288, 65536,
          (void*)(ATT + (long)c * 4 * 524288), 1024, 524288, 128,
          nullptr, 8, 512, 1.0f);
    }
    // output projection -> O32 (fp32)
    gemm_bt<1, false, false><<<dim3(64, 8, 1), dim3(256), 0, stream>>>(
        ATT, 1024, 0, 0, oWb, 1024, 0, 0, (void*)O32, 1024, 0, 0,
        ob + l * 1024, 1, 1024, 1.0f);
    if (!apply_pos) {
      if (qin_bf16)
        ln_kernel<true><<<dim3(8192), dim3(256), 0, stream>>>(
            Qin, O32, ln1_g + l * 1024, ln1_b + l * 1024, o32, o16);
      else
        ln_kernel<false><<<dim3(8192), dim3(256), 0, stream>>>(
            Qin, O32, ln1_g + l * 1024, ln1_b + l * 1024, o32, o16);
    } else {
      if (qin_bf16)
        ln_kernel<true><<<dim3(8192), dim3(256), 0, stream>>>(
            Qin, O32, ln1_g + l * 1024, ln1_b + l * 1024, X1, X1B);
      else
        ln_kernel<false><<<dim3(8192), dim3(256), 0, stream>>>(
            Qin, O32, ln1_g + l * 1024, ln1_b + l * 1024, X1, X1B);
      gemm_bt<1, true, true><<<dim3(64, 32, 1), dim3(256), 0, stream>>>(
          X1B, 1024, 0, 0, w1b, 1024, 0, 0, (void*)H1B, 4096, 0, 0,
          b1 + l * 4096, 1, 1024, 1.0f);
      gemm_bt<1, false, false><<<dim3(64, 8, 1), dim3(256), 0, stream>>>(
          H1B, 4096, 0, 0, w2b, 4096, 0, 0, (void*)O32, 1024, 0, 0,
          b2 + l * 1024, 1, 4096, 1.0f);
      ln_kernel<false><<<dim3(8192), dim3(256), 0, stream>>>(
          X1, O32, ln2_g + l * 1024, ln2_b + l * 1024, o32, o16);
    }
  };

  // gumbel bits for all layers
  bbit_kernel<<<dim3(48), dim3(256), 0, stream>>>(alphas, gumE, bbit, 12288);

  // layer 0: y = L0(qa, qa, qa), bmask=1, FFN. bf16(y) -> VB (layer2 values).
  cast_kernel<<<dim3(8192), dim3(256), 0, stream>>>(qa_emb, XB, ND);
  run_layer(0, qa_emb, false, XB, XB, true, 1, nullptr, VB);
  // layer 1: x = L1(q, q, q), bmask=1, no FFN. bf16(x) -> XB (layer2 q/k + residual).
  cast_kernel<<<dim3(8192), dim3(256), 0, stream>>>(q_emb, XB, ND);
  run_layer(1, q_emb, false, XB, XB, false, 1, nullptr, XB);
  // layer 2: out = L2(x, x, y), bmask=0 (zero_pad), FFN. residual read from bf16 XB.
  run_layer(2, XB, true, XB, VB, true, 0, outp, nullptr);
}

// Round 3
// 1505.784 us; speedup vs baseline: 1.0955x; 1.0955x over previous
//
#include <hip/hip_runtime.h>
#include <math.h>

#define NEGV -1e32f

typedef __bf16 bf16_t;
typedef _Float16 f16_t;
typedef __bf16 bf16x8 __attribute__((ext_vector_type(8)));
typedef __bf16 bf16x4 __attribute__((ext_vector_type(4)));
typedef _Float16 f16x8 __attribute__((ext_vector_type(8)));
typedef _Float16 f16x4 __attribute__((ext_vector_type(4)));
typedef float floatx4 __attribute__((ext_vector_type(4)));

// ---------------- wave helpers ----------------
static __device__ __forceinline__ float wave_sum(float v) {
#pragma unroll
  for (int d = 32; d > 0; d >>= 1) v += __shfl_xor(v, d, 64);
  return v;
}
static __device__ __forceinline__ float wave_max(float v) {
#pragma unroll
  for (int d = 32; d > 0; d >>= 1) v = fmaxf(v, __shfl_xor(v, d, 64));
  return v;
}

// async global->LDS, 16B per lane; LDS dest is wave-uniform base + lane*16
static __device__ __forceinline__ void gl2lds16(const bf16_t* g, bf16_t* l) {
  __builtin_amdgcn_global_load_lds((__attribute__((address_space(1))) void*)(void*)g,
                                   (__attribute__((address_space(3))) void*)l, 16, 0, 0);
}

// ---------------- GEMM: C[m,n] = alpha * sum_k A[m,k]*B[n,k] (+bias) ----------------
// A,B bf16 K-contiguous. 128x128 tile, BK=32, 256 threads (4 waves, 2x2 of 64x64).
// Batch z: operand offset = (z/zdiv)*so + (z%zdiv)*si  (element units).
// BIAS_MODE: 0 none, 1 per-col(n), 2 per-row(m). BIAS_Z0: bias only when zo==0 (split-K).
// OUT_MODE: 0 fp32, 1 bf16, 2 fp16.
// LDS columns XOR-swizzled (slot = kg ^ ((r&3)^((r>>2)&3))) to kill the 8-way
// ds_read_b128 bank conflict (row stride 64B = 16 banks); swizzle applied on the
// GLOBAL source side so global_load_lds lane-contiguity is preserved.
template <int BIAS_MODE, bool RELU, int OUT_MODE, bool BIAS_Z0>
__global__ __launch_bounds__(256) void gemm_bt(
    const bf16_t* __restrict__ A, long lda, long a_so, long a_si,
    const bf16_t* __restrict__ B, long ldb, long b_so, long b_si,
    void* __restrict__ Cv, long ldc, long c_so, long c_si,
    const float* __restrict__ bias, int zdiv, int K, float alpha)
{
  __shared__ bf16_t As[4096];  // 128 rows x 32 (bf16)
  __shared__ bf16_t Bs[4096];
  const int tid = threadIdx.x;
  const int wave = tid >> 6;
  const int lane = tid & 63;
  const int wr = wave >> 1;
  const int wc = wave & 1;
  const int z = blockIdx.z;
  const long zo = z / zdiv;
  const long zi = z % zdiv;
  A += zo * a_so + zi * a_si;
  B += zo * b_so + zi * b_si;
  const long m0 = (long)blockIdx.x * 128;
  const long n0 = (long)blockIdx.y * 128;

  // staging: row = tid>>2 ; column slot (tid&3) holds global k-group (tid&3)^swz(row)
  const int srow = tid >> 2;
  const int swzs = (srow & 3) ^ ((srow >> 2) & 3);
  const int scol = ((tid & 3) ^ swzs) * 8;
  const bf16_t* gA0 = A + (m0 + srow) * lda + scol;
  const bf16_t* gA1 = A + (m0 + srow + 64) * lda + scol;
  const bf16_t* gB0 = B + (n0 + srow) * ldb + scol;
  const bf16_t* gB1 = B + (n0 + srow + 64) * ldb + scol;
  bf16_t* lA0 = As + wave * 512;          // uniform per-wave base (lane*16B added by HW)
  bf16_t* lA1 = As + 2048 + wave * 512;
  bf16_t* lB0 = Bs + wave * 512;
  bf16_t* lB1 = Bs + 2048 + wave * 512;

  floatx4 acc[4][4] = {};
  const int lr = lane & 15;
  const int kg = lane >> 4;               // k-group 0..3 (8 elements each)
  const int sz = (lr & 3) ^ ((lr >> 2) & 3);
  const int kof = (kg ^ sz) * 8;          // swizzled column slot for this lane's rows

  for (int k0 = 0; k0 < K; k0 += 32) {
    gl2lds16(gA0 + k0, lA0);
    gl2lds16(gA1 + k0, lA1);
    gl2lds16(gB0 + k0, lB0);
    gl2lds16(gB1 + k0, lB1);
    __syncthreads();
    bf16x8 af[4], bfr[4];
#pragma unroll
    for (int t = 0; t < 4; ++t) {
      af[t]  = *(const bf16x8*)(As + (wr * 64 + t * 16 + lr) * 32 + kof);
      bfr[t] = *(const bf16x8*)(Bs + (wc * 64 + t * 16 + lr) * 32 + kof);
    }
#pragma unroll
    for (int tm = 0; tm < 4; ++tm)
#pragma unroll
      for (int tn = 0; tn < 4; ++tn)
        acc[tm][tn] = __builtin_amdgcn_mfma_f32_16x16x32_bf16(af[tm], bfr[tn], acc[tm][tn], 0, 0, 0);
    __syncthreads();
  }

  // epilogue: C/D layout col=lane&15, row=(lane>>4)*4+reg (m89-verified)
  const long coff = zo * c_so + zi * c_si;
  const int q4 = (lane >> 4) * 4;
  const bool do_bias = BIAS_MODE && (!BIAS_Z0 || zo == 0);
#pragma unroll
  for (int tm = 0; tm < 4; ++tm) {
#pragma unroll
    for (int tn = 0; tn < 4; ++tn) {
#pragma unroll
      for (int r = 0; r < 4; ++r) {
        const long row = m0 + wr * 64 + tm * 16 + q4 + r;
        const long col = n0 + wc * 64 + tn * 16 + lr;
        float v = acc[tm][tn][r] * alpha;
        if (BIAS_MODE == 1 && do_bias) v += bias[col];
        if (BIAS_MODE == 2 && do_bias) v += bias[row];
        if (RELU) v = fmaxf(v, 0.0f);
        const long idx = coff + row * ldc + col;
        if (OUT_MODE == 1)      ((bf16_t*)Cv)[idx] = (bf16_t)v;
        else if (OUT_MODE == 2) ((f16_t*)Cv)[idx]  = (f16_t)v;
        else                    ((float*)Cv)[idx]  = v;
      }
    }
  }
}

// ---------------- fp32 -> bf16 cast ----------------
__global__ __launch_bounds__(256) void cast_kernel(const float* __restrict__ in,
                                                   bf16_t* __restrict__ out, long n)
{
  const long i = ((long)blockIdx.x * 256 + threadIdx.x) * 4;
  if (i >= n) return;
  const float4 v = *(const float4*)(in + i);
  bf16x4 o;
  o[0] = (bf16_t)v.x; o[1] = (bf16_t)v.y; o[2] = (bf16_t)v.z; o[3] = (bf16_t)v.w;
  *(bf16x4*)(out + i) = o;
}

// ---------------- gumbel choice bits: b[l,h,s] = (logit0 >= logit1) ----------------
__global__ void bbit_kernel(const float* __restrict__ alphas, const float* __restrict__ E,
                            int* __restrict__ bbit, int n)
{
  const int i = blockIdx.x * 256 + threadIdx.x;
  if (i >= n) return;
  const float l0 = alphas[2 * i]     - logf(E[2 * i]     + 1e-5f);
  const float l1 = alphas[2 * i + 1] - logf(E[2 * i + 1] + 1e-5f);
  bbit[i] = (l0 >= l1) ? 1 : 0;
}

// ---------------- LayerNorm(X + R1 + R2) * g + b ; one block per 1024-row ----------
// X fp32 or bf16 (XBF); R1/R2 are the two fp16 split-K partials. out32/out16 nullable.
template <bool XBF>
__global__ __launch_bounds__(256) void ln_kernel(
    const void* __restrict__ Xv, const f16_t* __restrict__ R1,
    const f16_t* __restrict__ R2,
    const float* __restrict__ g, const float* __restrict__ b,
    float* __restrict__ out32, bf16_t* __restrict__ out16)
{
  const long row = blockIdx.x;
  const int t = threadIdx.x;
  float x0, x1, x2, x3;
  if (XBF) {
    const bf16x4 xv = *(const bf16x4*)((const bf16_t*)Xv + row * 1024 + t * 4);
    x0 = (float)xv[0]; x1 = (float)xv[1]; x2 = (float)xv[2]; x3 = (float)xv[3];
  } else {
    const float4 xv = *(const float4*)((const float*)Xv + row * 1024 + t * 4);
    x0 = xv.x; x1 = xv.y; x2 = xv.z; x3 = xv.w;
  }
  const f16x4 r1 = *(const f16x4*)(R1 + row * 1024 + t * 4);
  const f16x4 r2 = *(const f16x4*)(R2 + row * 1024 + t * 4);
  const float v0 = x0 + (float)r1[0] + (float)r2[0];
  const float v1 = x1 + (float)r1[1] + (float)r2[1];
  const float v2 = x2 + (float)r1[2] + (float)r2[2];
  const float v3 = x3 + (float)r1[3] + (float)r2[3];
  float s  = v0 + v1 + v2 + v3;
  float s2 = v0 * v0 + v1 * v1 + v2 * v2 + v3 * v3;
  s = wave_sum(s); s2 = wave_sum(s2);
  __shared__ float red[8];
  const int wv = t >> 6, lane = t & 63;
  if (lane == 0) { red[wv] = s; red[4 + wv] = s2; }
  __syncthreads();
  s  = red[0] + red[1] + red[2] + red[3];
  s2 = red[4] + red[5] + red[6] + red[7];
  const float mu = s * (1.0f / 1024.0f);
  const float var = s2 * (1.0f / 1024.0f) - mu * mu;
  const float rstd = rsqrtf(var + 1e-5f);
  const float4 gv = *(const float4*)(g + t * 4);
  const float4 bv = *(const float4*)(b + t * 4);
  float4 ov;
  ov.x = (v0 - mu) * rstd * gv.x + bv.x;
  ov.y = (v1 - mu) * rstd * gv.y + bv.y;
  ov.z = (v2 - mu) * rstd * gv.z + bv.z;
  ov.w = (v3 - mu) * rstd * gv.w + bv.w;
  if (out32) *(float4*)(out32 + row * 1024 + t * 4) = ov;
  if (out16) {
    bf16x4 oh;
    oh[0] = (bf16_t)ov.x; oh[1] = (bf16_t)ov.y; oh[2] = (bf16_t)ov.z; oh[3] = (bf16_t)ov.w;
    *(bf16x4*)(out16 + row * 1024 + t * 4) = oh;
  }
}

// ---------------- attention mid: per row of S (512), one wave per row ----------------
// dam[h,i,j] = (j<i+bmask) || b[h,j-i]==0 ; band = j<i+bmask
// p = softmax(dam? s : NEG); sc = band? p : 0; c = cumsum(sc); tot = sum(sc)
// te = clip(exp(sqrt(max((tot-c)*|i-j|,0)) * (-softplus(gamma_h))), 1e-5, 1e5)
// P = softmax(band? s*te : NEG); zero_pad zeroes row i==0.  S is fp16.
__global__ __launch_bounds__(256) void attn_mid(
    const f16_t* __restrict__ S, bf16_t* __restrict__ P,
    const int* __restrict__ bbit, const float* __restrict__ gam,
    const int bmask, const int zero_pad, const int bh0)
{
  const int wid = threadIdx.x >> 6;
  const int lane = threadIdx.x & 63;
  const long rowid = (long)blockIdx.x * 4 + wid;
  const int i = (int)(rowid & 511);
  const int bh_local = (int)(rowid >> 9);
  const int h = (bh0 + bh_local) & 7;
  const f16_t* s = S + rowid * 512;
  const int jb = lane * 8;

  const float gv = gam[h];
  const float gamma = -log1pf(expf(gv));  // -softplus

  float sv[8];
  {
    const f16x8 a = *(const f16x8*)(s + jb);
#pragma unroll
    for (int u = 0; u < 8; ++u) sv[u] = (float)a[u];
  }
  const int* bb = bbit + h * 512;
  float z[8];
  bool band[8];
  float m1 = NEGV;
#pragma unroll
  for (int u = 0; u < 8; ++u) {
    const int j = jb + u;
    const bool bd = j < i + bmask;
    band[u] = bd;
    int d = j - i; d = d < 0 ? 0 : d;
    const bool allowed = bd || (bb[d] == 0);
    z[u] = allowed ? sv[u] : NEGV;
    m1 = fmaxf(m1, z[u]);
  }
  m1 = wave_max(m1);
  float e[8], es = 0.f;
#pragma unroll
  for (int u = 0; u < 8; ++u) { e[u] = expf(z[u] - m1); es += e[u]; }
  es = wave_sum(es);
  const float inv1 = 1.0f / es;

  float c[8];
  float run = 0.f;
#pragma unroll
  for (int u = 0; u < 8; ++u) {
    const float p = band[u] ? e[u] * inv1 : 0.f;
    run += p;
    c[u] = run;
  }
  float x = run;
#pragma unroll
  for (int d = 1; d < 64; d <<= 1) {
    const float y = __shfl_up(x, (unsigned)d, 64);
    if (lane >= d) x += y;
  }
  const float tot = __shfl(x, 63, 64);
  const float ex = x - run;  // exclusive prefix across lanes

  float z2[8];
  float m2 = NEGV;
#pragma unroll
  for (int u = 0; u < 8; ++u) {
    const int j = jb + u;
    const float cc = c[u] + ex;
    const float pos = fabsf((float)(i - j));
    const float dist = sqrtf(fmaxf((tot - cc) * pos, 0.f));
    float te = expf(dist * gamma);
    te = fminf(fmaxf(te, 1e-5f), 1e5f);
    z2[u] = band[u] ? sv[u] * te : NEGV;
    m2 = fmaxf(m2, z2[u]);
  }
  m2 = wave_max(m2);
  float f[8], es2 = 0.f;
#pragma unroll
  for (int u = 0; u < 8; ++u) { f[u] = expf(z2[u] - m2); es2 += f[u]; }
  es2 = wave_sum(es2);
  const float inv2 = (zero_pad && i == 0) ? 0.f : (1.0f / es2);
  bf16x8 o;
#pragma unroll
  for (int u = 0; u < 8; ++u) o[u] = (bf16_t)(f[u] * inv2);
  *(bf16x8*)(P + rowid * 512 + jb) = o;
}

// ---------------- host ----------------
extern "C" void kernel_launch(void* const* d_in, const int* in_sizes, int n_in,
                              void* d_out, int out_size, void* d_ws, size_t ws_size,
                              hipStream_t stream)
{
  (void)in_sizes; (void)n_in; (void)out_size; (void)ws_size;
  const float* q_emb  = (const float*)d_in[0];
  const float* qa_emb = (const float*)d_in[1];
  const float* kW = (const float*)d_in[2];
  const float* kb = (const float*)d_in[3];
  const float* vW = (const float*)d_in[4];
  const float* vb = (const float*)d_in[5];
  const float* oW = (const float*)d_in[6];
  const float* ob = (const float*)d_in[7];
  const float* gammas = (const float*)d_in[8];
  const float* alphas = (const float*)d_in[9];
  const float* ln1_g = (const float*)d_in[10];
  const float* ln1_b = (const float*)d_in[11];
  const float* w1 = (const float*)d_in[12];
  const float* b1 = (const float*)d_in[13];
  const float* w2 = (const float*)d_in[14];
  const float* b2 = (const float*)d_in[15];
  const float* ln2_g = (const float*)d_in[16];
  const float* ln2_b = (const float*)d_in[17];
  const float* gumE = (const float*)d_in[18];
  float* outp = (float*)d_out;

  // ---- workspace overlay (peak 168 MB) ----
  // persistent: bbit@0, VB@1M(16), XB@17M(16), weights 33..55M
  // attn:  KQB@56(16) VT@72(16) SS(f16)@88(32) PP@120(32) ATT@152(16)
  // oproj: O16a@56(16) O16b@72(16)   [KQB/VT dead]
  // ln1:   X1B@88(16)                [SS dead]
  // ffn1:  H1B@104(64)               [PP/ATT dead]
  // ffn2:  O16c@56(16) O16d@72(16)   [O16a/b dead]
  const size_t MBc = 1ull << 20;
  char* W = (char*)d_ws;
  int*    bbit = (int*)W;
  bf16_t* VB   = (bf16_t*)(W + 1 * MBc);
  bf16_t* XB   = (bf16_t*)(W + 17 * MBc);
  bf16_t* kWb  = (bf16_t*)(W + 33 * MBc);
  bf16_t* vWb  = (bf16_t*)(W + 35 * MBc);
  bf16_t* oWb  = (bf16_t*)(W + 37 * MBc);
  bf16_t* w1b  = (bf16_t*)(W + 39 * MBc);
  bf16_t* w2b  = (bf16_t*)(W + 47 * MBc);
  bf16_t* KQB  = (bf16_t*)(W + 56 * MBc);
  bf16_t* VT   = (bf16_t*)(W + 72 * MBc);
  f16_t*  SS   = (f16_t*)(W + 88 * MBc);
  bf16_t* PP   = (bf16_t*)(W + 120 * MBc);
  bf16_t* ATT  = (bf16_t*)(W + 152 * MBc);
  f16_t*  O16a = (f16_t*)(W + 56 * MBc);   // split-K partials (o-proj, then ffn2)
  bf16_t* X1B  = (bf16_t*)(W + 88 * MBc);
  bf16_t* H1B  = (bf16_t*)(W + 104 * MBc);

  const long ND = 8388608;  // B*S*D

  auto run_layer = [&](int l, const void* Qin, bool qin_bf16, const bf16_t* XBp,
                       const bf16_t* VBp, bool apply_pos, int bmask,
                       float* o32, bf16_t* o16) {
    // per-layer weight casts into fixed bf16 buffers
    cast_kernel<<<dim3(1024), dim3(256), 0, stream>>>(kW + (long)l * 1048576, kWb, 1048576);
    cast_kernel<<<dim3(1024), dim3(256), 0, stream>>>(vW + (long)l * 1048576, vWb, 1048576);
    cast_kernel<<<dim3(1024), dim3(256), 0, stream>>>(oW + (long)l * 1048576, oWb, 1048576);
    cast_kernel<<<dim3(4096), dim3(256), 0, stream>>>(w1 + (long)l * 4194304, w1b, 4194304);
    cast_kernel<<<dim3(4096), dim3(256), 0, stream>>>(w2 + (long)l * 4194304, w2b, 4194304);

    // q==k projection: (8192x1024)x(1024x1024)^T + kb -> KQB bf16
    gemm_bt<1, false, 1, false><<<dim3(64, 8, 1), dim3(256), 0, stream>>>(
        XBp, 1024, 0, 0, kWb, 1024, 0, 0, (void*)KQB, 1024, 0, 0,
        kb + l * 1024, 1, 1024, 1.0f);
    // V^T projection: per batch b, C[d,s] = sum_k vW[d,k]*X[s,k] + vb[d]
    gemm_bt<2, false, 1, false><<<dim3(8, 4, 16), dim3(256), 0, stream>>>(
        vWb, 1024, 0, 0, VBp, 1024, 524288, 0, (void*)VT, 512, 524288, 0,
        vb + l * 1024, 1, 1024, 1.0f);
    const int zp = (bmask == 0) ? 1 : 0;
    for (int c = 0; c < 2; ++c) {  // 64 (b,h) pairs per chunk = 8 full batches
      const bf16_t* kqc = KQB + (long)c * 4194304;
      // S = Q K^T / sqrt(128) -> fp16  (z: /8 -> batch, %8 -> head)
      gemm_bt<0, false, 2, false><<<dim3(4, 4, 64), dim3(256), 0, stream>>>(
          kqc, 1024, 524288, 128, kqc, 1024, 524288, 128,
          (void*)SS, 512, 2097152, 262144, nullptr, 8, 128, 0.08838834764831845f);
      attn_mid<<<dim3(8192), dim3(256), 0, stream>>>(
          SS, PP, bbit + l * 4096, gammas + l * 8, bmask, zp, c * 64);
      // att = P V : A=P (512x512 bf16), B=V^T (128x512), C->(B,S,H*DK) bf16
      gemm_bt<0, false, 1, false><<<dim3(4, 1, 64), dim3(256), 0, stream>>>(
          PP, 512, 2097152, 262144, VT + (long)c * 4194304, 512, 524288, 65536,
          (void*)(ATT + (long)c * 4194304), 1024, 524288, 128,
          nullptr, 8, 512, 1.0f);
    }
    // output projection, split-K=2 -> fp16 partials O16a / O16a+8M
    gemm_bt<1, false, 2, true><<<dim3(64, 8, 2), dim3(256), 0, stream>>>(
        ATT, 1024, 512, 0, oWb, 1024, 512, 0, (void*)O16a, 1024, 8388608, 0,
        ob + l * 1024, 1, 512, 1.0f);
    if (!apply_pos) {
      if (qin_bf16)
        ln_kernel<true><<<dim3(8192), dim3(256), 0, stream>>>(
            Qin, O16a, O16a + 8388608, ln1_g + l * 1024, ln1_b + l * 1024, o32, o16);
      else
        ln_kernel<false><<<dim3(8192), dim3(256), 0, stream>>>(
            Qin, O16a, O16a + 8388608, ln1_g + l * 1024, ln1_b + l * 1024, o32, o16);
    } else {
      if (qin_bf16)
        ln_kernel<true><<<dim3(8192), dim3(256), 0, stream>>>(
            Qin, O16a, O16a + 8388608, ln1_g + l * 1024, ln1_b + l * 1024, nullptr, X1B);
      else
        ln_kernel<false><<<dim3(8192), dim3(256), 0, stream>>>(
            Qin, O16a, O16a + 8388608, ln1_g + l * 1024, ln1_b + l * 1024, nullptr, X1B);
      gemm_bt<1, true, 1, false><<<dim3(64, 32, 1), dim3(256), 0, stream>>>(
          X1B, 1024, 0, 0, w1b, 1024, 0, 0, (void*)H1B, 4096, 0, 0,
          b1 + l * 4096, 1, 1024, 1.0f);
      // FFN2 split-K=2 -> fp16 partials (reuse O16a slots; o-proj partials dead)
      gemm_bt<1, false, 2, true><<<dim3(64, 8, 2), dim3(256), 0, stream>>>(
          H1B, 4096, 2048, 0, w2b, 4096, 2048, 0, (void*)O16a, 1024, 8388608, 0,
          b2 + l * 1024, 1, 2048, 1.0f);
      ln_kernel<true><<<dim3(8192), dim3(256), 0, stream>>>(
          X1B, O16a, O16a + 8388608, ln2_g + l * 1024, ln2_b + l * 1024, o32, o16);
    }
  };

  // gumbel bits for all layers
  bbit_kernel<<<dim3(48), dim3(256), 0, stream>>>(alphas, gumE, bbit, 12288);

  // layer 0: y = L0(qa, qa, qa), bmask=1, FFN. bf16(y) -> VB (layer2 values).
  cast_kernel<<<dim3(8192), dim3(256), 0, stream>>>(qa_emb, XB, ND);
  run_layer(0, qa_emb, false, XB, XB, true, 1, nullptr, VB);
  // layer 1: x = L1(q, q, q), bmask=1, no FFN. bf16(x) -> XB (layer2 q/k + residual).
  cast_kernel<<<dim3(8192), dim3(256), 0, stream>>>(q_emb, XB, ND);
  run_layer(1, q_emb, false, XB, XB, false, 1, nullptr, XB);
  // layer 2: out = L2(x, x, y), bmask=0 (zero_pad), FFN. residual read from bf16 XB.
  run_layer(2, XB, true, XB, VB, true, 0, outp, nullptr);
}

// Round 4
// 1305.107 us; speedup vs baseline: 1.2639x; 1.1538x over previous
//
#include <hip/hip_runtime.h>
#include <math.h>

#define NEGV -1e32f

typedef __bf16 bf16_t;
typedef _Float16 f16_t;
typedef __bf16 bf16x8 __attribute__((ext_vector_type(8)));
typedef __bf16 bf16x4 __attribute__((ext_vector_type(4)));
typedef _Float16 f16x8 __attribute__((ext_vector_type(8)));
typedef float floatx4 __attribute__((ext_vector_type(4)));

// ---------------- wave helpers ----------------
static __device__ __forceinline__ float wave_sum(float v) {
#pragma unroll
  for (int d = 32; d > 0; d >>= 1) v += __shfl_xor(v, d, 64);
  return v;
}
static __device__ __forceinline__ float wave_max(float v) {
#pragma unroll
  for (int d = 32; d > 0; d >>= 1) v = fmaxf(v, __shfl_xor(v, d, 64));
  return v;
}

// async global->LDS, 16B per lane; LDS dest is wave-uniform base + lane*16
static __device__ __forceinline__ void gl2lds16(const bf16_t* g, bf16_t* l) {
  __builtin_amdgcn_global_load_lds((__attribute__((address_space(1))) void*)(void*)g,
                                   (__attribute__((address_space(3))) void*)l, 16, 0, 0);
}

// ---------------- GEMM: C[m,n] = alpha * sum_k A[m,k]*B[n,k] (+bias) ----------------
// A,B bf16 K-contiguous. 128x128 tile, BK=64, 256 threads (4 waves, 2x2 of 64x64).
// K must be a multiple of 64.
// LDS layout: row stride 64 elems (128B); 8 column slots of 8 elems; data for
// logical k-group g of row r stored at physical slot g ^ (r&7). Swizzle is applied
// on the GLOBAL source column so global_load_lds stays lane-contiguous; per 16-lane
// MFMA group each bank-quad serves exactly 2 lanes (free per m136).
// Batch z: operand offset = (z/zdiv)*so + (z%zdiv)*si (element units).
// BIAS_MODE: 0 none, 1 per-col(n), 2 per-row(m). OUT_MODE: 0 fp32, 1 bf16, 2 fp16.
template <int BIAS_MODE, bool RELU, int OUT_MODE>
__global__ __launch_bounds__(256) void gemm_bt(
    const bf16_t* __restrict__ A, long lda, long a_so, long a_si,
    const bf16_t* __restrict__ B, long ldb, long b_so, long b_si,
    void* __restrict__ Cv, long ldc, long c_so, long c_si,
    const float* __restrict__ bias, int zdiv, int K, float alpha)
{
  __shared__ bf16_t As[8192];  // 128 rows x 64
  __shared__ bf16_t Bs[8192];
  const int tid = threadIdx.x;
  const int wave = tid >> 6;
  const int lane = tid & 63;
  const int wr = wave >> 1;
  const int wc = wave & 1;
  const int z = blockIdx.z;
  const long zo = z / zdiv;
  const long zi = z % zdiv;
  A += zo * a_so + zi * a_si;
  B += zo * b_so + zi * b_si;
  const long m0 = (long)blockIdx.x * 128;
  const long n0 = (long)blockIdx.y * 128;

  // staging: 4 rounds of 32 rows; thread -> row r*32+(tid>>3), slot tid&7,
  // global col = (slot ^ (row&7))*8  (row&7 == (tid>>3)&7 since r*32 % 8 == 0)
  const int srow = tid >> 3;
  const int scol = ((tid & 7) ^ (srow & 7)) * 8;
  const bf16_t* gA = A + (m0 + srow) * lda + scol;
  const bf16_t* gB = B + (n0 + srow) * ldb + scol;
  bf16_t* lA = As + wave * 512;  // wave-uniform base; + r*2048 per round
  bf16_t* lB = Bs + wave * 512;

  floatx4 acc[4][4] = {};
  const int lr = lane & 15;
  const int kg = lane >> 4;  // k-group within half (8 elems each)

  for (int k0 = 0; k0 < K; k0 += 64) {
#pragma unroll
    for (int r = 0; r < 4; ++r) {
      gl2lds16(gA + (long)r * 32 * lda + k0, lA + r * 2048);
      gl2lds16(gB + (long)r * 32 * ldb + k0, lB + r * 2048);
    }
    __syncthreads();
#pragma unroll
    for (int h = 0; h < 2; ++h) {
      const int slot = ((h * 4 + kg) ^ (lr & 7)) * 8;
      bf16x8 af[4], bfr[4];
#pragma unroll
      for (int t = 0; t < 4; ++t) {
        af[t]  = *(const bf16x8*)(As + (wr * 64 + t * 16 + lr) * 64 + slot);
        bfr[t] = *(const bf16x8*)(Bs + (wc * 64 + t * 16 + lr) * 64 + slot);
      }
#pragma unroll
      for (int tm = 0; tm < 4; ++tm)
#pragma unroll
        for (int tn = 0; tn < 4; ++tn)
          acc[tm][tn] = __builtin_amdgcn_mfma_f32_16x16x32_bf16(af[tm], bfr[tn], acc[tm][tn], 0, 0, 0);
    }
    __syncthreads();
  }

  // epilogue: C/D layout col=lane&15, row=(lane>>4)*4+reg (m89-verified)
  const long coff = zo * c_so + zi * c_si;
  const int q4 = (lane >> 4) * 4;
#pragma unroll
  for (int tm = 0; tm < 4; ++tm) {
#pragma unroll
    for (int tn = 0; tn < 4; ++tn) {
#pragma unroll
      for (int r = 0; r < 4; ++r) {
        const long row = m0 + wr * 64 + tm * 16 + q4 + r;
        const long col = n0 + wc * 64 + tn * 16 + lr;
        float v = acc[tm][tn][r] * alpha;
        if (BIAS_MODE == 1) v += bias[col];
        if (BIAS_MODE == 2) v += bias[row];
        if (RELU) v = fmaxf(v, 0.0f);
        const long idx = coff + row * ldc + col;
        if (OUT_MODE == 1)      ((bf16_t*)Cv)[idx] = (bf16_t)v;
        else if (OUT_MODE == 2) ((f16_t*)Cv)[idx]  = (f16_t)v;
        else                    ((float*)Cv)[idx]  = v;
      }
    }
  }
}

// ---------------- fp32 -> bf16 cast ----------------
__global__ __launch_bounds__(256) void cast_kernel(const float* __restrict__ in,
                                                   bf16_t* __restrict__ out, long n)
{
  const long i = ((long)blockIdx.x * 256 + threadIdx.x) * 4;
  if (i >= n) return;
  const float4 v = *(const float4*)(in + i);
  bf16x4 o;
  o[0] = (bf16_t)v.x; o[1] = (bf16_t)v.y; o[2] = (bf16_t)v.z; o[3] = (bf16_t)v.w;
  *(bf16x4*)(out + i) = o;
}

// ---------------- gumbel choice bits: b[l,h,s] = (logit0 >= logit1) ----------------
__global__ void bbit_kernel(const float* __restrict__ alphas, const float* __restrict__ E,
                            int* __restrict__ bbit, int n)
{
  const int i = blockIdx.x * 256 + threadIdx.x;
  if (i >= n) return;
  const float l0 = alphas[2 * i]     - logf(E[2 * i]     + 1e-5f);
  const float l1 = alphas[2 * i + 1] - logf(E[2 * i + 1] + 1e-5f);
  bbit[i] = (l0 >= l1) ? 1 : 0;
}

// ---------------- LayerNorm(X + R) * g + b ; one block per 1024-row ----------------
// X (residual) fp32 or bf16 per XBF; R fp32. out32/out16 nullable.
template <bool XBF>
__global__ __launch_bounds__(256) void ln_kernel(
    const void* __restrict__ Xv, const float* __restrict__ R,
    const float* __restrict__ g, const float* __restrict__ b,
    float* __restrict__ out32, bf16_t* __restrict__ out16)
{
  const long row = blockIdx.x;
  const int t = threadIdx.x;
  float x0, x1, x2, x3;
  if (XBF) {
    const bf16x4 xv = *(const bf16x4*)((const bf16_t*)Xv + row * 1024 + t * 4);
    x0 = (float)xv[0]; x1 = (float)xv[1]; x2 = (float)xv[2]; x3 = (float)xv[3];
  } else {
    const float4 xv = *(const float4*)((const float*)Xv + row * 1024 + t * 4);
    x0 = xv.x; x1 = xv.y; x2 = xv.z; x3 = xv.w;
  }
  const float4 rv = *(const float4*)(R + row * 1024 + t * 4);
  const float v0 = x0 + rv.x, v1 = x1 + rv.y, v2 = x2 + rv.z, v3 = x3 + rv.w;
  float s  = v0 + v1 + v2 + v3;
  float s2 = v0 * v0 + v1 * v1 + v2 * v2 + v3 * v3;
  s = wave_sum(s); s2 = wave_sum(s2);
  __shared__ float red[8];
  const int wv = t >> 6, lane = t & 63;
  if (lane == 0) { red[wv] = s; red[4 + wv] = s2; }
  __syncthreads();
  s  = red[0] + red[1] + red[2] + red[3];
  s2 = red[4] + red[5] + red[6] + red[7];
  const float mu = s * (1.0f / 1024.0f);
  const float var = s2 * (1.0f / 1024.0f) - mu * mu;
  const float rstd = rsqrtf(var + 1e-5f);
  const float4 gv = *(const float4*)(g + t * 4);
  const float4 bv = *(const float4*)(b + t * 4);
  float4 ov;
  ov.x = (v0 - mu) * rstd * gv.x + bv.x;
  ov.y = (v1 - mu) * rstd * gv.y + bv.y;
  ov.z = (v2 - mu) * rstd * gv.z + bv.z;
  ov.w = (v3 - mu) * rstd * gv.w + bv.w;
  if (out32) *(float4*)(out32 + row * 1024 + t * 4) = ov;
  if (out16) {
    bf16x4 oh;
    oh[0] = (bf16_t)ov.x; oh[1] = (bf16_t)ov.y; oh[2] = (bf16_t)ov.z; oh[3] = (bf16_t)ov.w;
    *(bf16x4*)(out16 + row * 1024 + t * 4) = oh;
  }
}

// ---------------- attention mid: one wave per S-row; IN-PLACE (fp16 in, bf16 out) ----
// dam[h,i,j] = (j<i+bmask) || b[h,j-i]==0 ; band = j<i+bmask
// p = softmax(dam? s : NEG); sc = band? p : 0; c = cumsum(sc); tot = sum(sc)
// te = clip(exp(sqrt(max((tot-c)*|i-j|,0)) * (-softplus(gamma_h))), 1e-5, 1e5)
// P = softmax(band? s*te : NEG); zero_pad zeroes row i==0.
__global__ __launch_bounds__(256) void attn_mid(
    const f16_t* __restrict__ S, bf16_t* __restrict__ P,
    const int* __restrict__ bbit, const float* __restrict__ gam,
    const int bmask, const int zero_pad)
{
  const int wid = threadIdx.x >> 6;
  const int lane = threadIdx.x & 63;
  const long rowid = (long)blockIdx.x * 4 + wid;
  const int i = (int)(rowid & 511);
  const int h = (int)(rowid >> 9) & 7;
  const f16_t* s = S + rowid * 512;
  const int jb = lane * 8;

  const float gv = gam[h];
  const float gamma = -log1pf(expf(gv));  // -softplus

  float sv[8];
  {
    const f16x8 a = *(const f16x8*)(s + jb);
#pragma unroll
    for (int u = 0; u < 8; ++u) sv[u] = (float)a[u];
  }
  const int* bb = bbit + h * 512;
  float z[8];
  bool band[8];
  float m1 = NEGV;
#pragma unroll
  for (int u = 0; u < 8; ++u) {
    const int j = jb + u;
    const bool bd = j < i + bmask;
    band[u] = bd;
    int d = j - i; d = d < 0 ? 0 : d;
    const bool allowed = bd || (bb[d] == 0);
    z[u] = allowed ? sv[u] : NEGV;
    m1 = fmaxf(m1, z[u]);
  }
  m1 = wave_max(m1);
  float e[8], es = 0.f;
#pragma unroll
  for (int u = 0; u < 8; ++u) { e[u] = expf(z[u] - m1); es += e[u]; }
  es = wave_sum(es);
  const float inv1 = 1.0f / es;

  float c[8];
  float run = 0.f;
#pragma unroll
  for (int u = 0; u < 8; ++u) {
    const float p = band[u] ? e[u] * inv1 : 0.f;
    run += p;
    c[u] = run;
  }
  float x = run;
#pragma unroll
  for (int d = 1; d < 64; d <<= 1) {
    const float y = __shfl_up(x, (unsigned)d, 64);
    if (lane >= d) x += y;
  }
  const float tot = __shfl(x, 63, 64);
  const float ex = x - run;  // exclusive prefix across lanes

  float z2[8];
  float m2 = NEGV;
#pragma unroll
  for (int u = 0; u < 8; ++u) {
    const int j = jb + u;
    const float cc = c[u] + ex;
    const float pos = fabsf((float)(i - j));
    const float dist = sqrtf(fmaxf((tot - cc) * pos, 0.f));
    float te = expf(dist * gamma);
    te = fminf(fmaxf(te, 1e-5f), 1e5f);
    z2[u] = band[u] ? sv[u] * te : NEGV;
    m2 = fmaxf(m2, z2[u]);
  }
  m2 = wave_max(m2);
  float f[8], es2 = 0.f;
#pragma unroll
  for (int u = 0; u < 8; ++u) { f[u] = expf(z2[u] - m2); es2 += f[u]; }
  es2 = wave_sum(es2);
  const float inv2 = (zero_pad && i == 0) ? 0.f : (1.0f / es2);
  bf16x8 o;
#pragma unroll
  for (int u = 0; u < 8; ++u) o[u] = (bf16_t)(f[u] * inv2);
  *(bf16x8*)(P + rowid * 512 + jb) = o;
}

// ---------------- host ----------------
extern "C" void kernel_launch(void* const* d_in, const int* in_sizes, int n_in,
                              void* d_out, int out_size, void* d_ws, size_t ws_size,
                              hipStream_t stream)
{
  (void)in_sizes; (void)n_in; (void)out_size; (void)ws_size;
  const float* q_emb  = (const float*)d_in[0];
  const float* qa_emb = (const float*)d_in[1];
  const float* kW = (const float*)d_in[2];
  const float* kb = (const float*)d_in[3];
  const float* vW = (const float*)d_in[4];
  const float* vb = (const float*)d_in[5];
  const float* oW = (const float*)d_in[6];
  const float* ob = (const float*)d_in[7];
  const float* gammas = (const float*)d_in[8];
  const float* alphas = (const float*)d_in[9];
  const float* ln1_g = (const float*)d_in[10];
  const float* ln1_b = (const float*)d_in[11];
  const float* w1 = (const float*)d_in[12];
  const float* b1 = (const float*)d_in[13];
  const float* w2 = (const float*)d_in[14];
  const float* b2 = (const float*)d_in[15];
  const float* ln2_g = (const float*)d_in[16];
  const float* ln2_b = (const float*)d_in[17];
  const float* gumE = (const float*)d_in[18];
  float* outp = (float*)d_out;

  // ---- workspace overlay (peak 179 MB) ----
  // persistent: bbit@0, VB@1M(16), XB@17M(16), kWb@33(6) vWb@39(6) oWb@45(6),
  //             w1b@51(8, per-layer), w2b@59(8, per-layer)
  // attn:  KQB@67(16) VT@83(16) SSPP@99(64, fp16 S then bf16 P in-place) ATT@163(16)
  // oproj: O32@67(32)   [KQB/VT dead]
  // ln1:   X1B@99(16)   [SSPP dead]
  // ffn1:  H1B@115(64)  [SSPP tail + ATT dead]
  // ffn2:  O32@67(32)
  const size_t MBc = 1ull << 20;
  char* W = (char*)d_ws;
  int*    bbit = (int*)W;
  bf16_t* VB   = (bf16_t*)(W + 1 * MBc);
  bf16_t* XB   = (bf16_t*)(W + 17 * MBc);
  bf16_t* kWb  = (bf16_t*)(W + 33 * MBc);
  bf16_t* vWb  = (bf16_t*)(W + 39 * MBc);
  bf16_t* oWb  = (bf16_t*)(W + 45 * MBc);
  bf16_t* w1b  = (bf16_t*)(W + 51 * MBc);
  bf16_t* w2b  = (bf16_t*)(W + 59 * MBc);
  bf16_t* KQB  = (bf16_t*)(W + 67 * MBc);
  bf16_t* VT   = (bf16_t*)(W + 83 * MBc);
  f16_t*  SSPP = (f16_t*)(W + 99 * MBc);
  bf16_t* PPb  = (bf16_t*)(W + 99 * MBc);   // bf16 view of same region
  bf16_t* ATT  = (bf16_t*)(W + 163 * MBc);
  float*  O32  = (float*)(W + 67 * MBc);
  bf16_t* X1B  = (bf16_t*)(W + 99 * MBc);
  bf16_t* H1B  = (bf16_t*)(W + 115 * MBc);

  const long ND = 8388608;  // B*S*D

  auto run_layer = [&](int l, const void* Qin, bool qin_bf16, const bf16_t* XBp,
                       const bf16_t* VBp, bool apply_pos, int bmask,
                       float* o32, bf16_t* o16) {
    const bf16_t* kWl = kWb + (long)l * 1048576;
    const bf16_t* vWl = vWb + (long)l * 1048576;
    const bf16_t* oWl = oWb + (long)l * 1048576;
    // q==k projection: (8192x1024)x(1024x1024)^T + kb -> KQB bf16 (B,S,H,DK)
    gemm_bt<1, false, 1><<<dim3(64, 8, 1), dim3(256), 0, stream>>>(
        XBp, 1024, 0, 0, kWl, 1024, 0, 0, (void*)KQB, 1024, 0, 0,
        kb + l * 1024, 1, 1024, 1.0f);
    // V^T projection: per batch b, C[d,s] = sum_k vW[d,k]*X[s,k] + vb[d]
    gemm_bt<2, false, 1><<<dim3(8, 4, 16), dim3(256), 0, stream>>>(
        vWl, 1024, 0, 0, VBp, 1024, 524288, 0, (void*)VT, 512, 524288, 0,
        vb + l * 1024, 1, 1024, 1.0f);
    const int zp = (bmask == 0) ? 1 : 0;
    // S = Q K^T / sqrt(128) -> fp16, all 128 bh in one dispatch
    gemm_bt<0, false, 2><<<dim3(4, 4, 128), dim3(256), 0, stream>>>(
        KQB, 1024, 524288, 128, KQB, 1024, 524288, 128,
        (void*)SSPP, 512, 2097152, 262144, nullptr, 8, 128, 0.08838834764831845f);
    attn_mid<<<dim3(16384), dim3(256), 0, stream>>>(
        SSPP, PPb, bbit + l * 4096, gammas + l * 8, bmask, zp);
    // att = P V : A=P (512x512 bf16, in-place), B=V^T (128x512) -> ATT (B,S,H*DK)
    gemm_bt<0, false, 1><<<dim3(4, 1, 128), dim3(256), 0, stream>>>(
        PPb, 512, 2097152, 262144, VT, 512, 524288, 65536,
        (void*)ATT, 1024, 524288, 128, nullptr, 8, 512, 1.0f);
    // output projection -> O32 fp32
    gemm_bt<1, false, 0><<<dim3(64, 8, 1), dim3(256), 0, stream>>>(
        ATT, 1024, 0, 0, oWl, 1024, 0, 0, (void*)O32, 1024, 0, 0,
        ob + l * 1024, 1, 1024, 1.0f);
    if (!apply_pos) {
      if (qin_bf16)
        ln_kernel<true><<<dim3(8192), dim3(256), 0, stream>>>(
            Qin, O32, ln1_g + l * 1024, ln1_b + l * 1024, o32, o16);
      else
        ln_kernel<false><<<dim3(8192), dim3(256), 0, stream>>>(
            Qin, O32, ln1_g + l * 1024, ln1_b + l * 1024, o32, o16);
    } else {
      // per-layer FFN weight casts
      cast_kernel<<<dim3(4096), dim3(256), 0, stream>>>(w1 + (long)l * 4194304, w1b, 4194304);
      cast_kernel<<<dim3(4096), dim3(256), 0, stream>>>(w2 + (long)l * 4194304, w2b, 4194304);
      if (qin_bf16)
        ln_kernel<true><<<dim3(8192), dim3(256), 0, stream>>>(
            Qin, O32, ln1_g + l * 1024, ln1_b + l * 1024, nullptr, X1B);
      else
        ln_kernel<false><<<dim3(8192), dim3(256), 0, stream>>>(
            Qin, O32, ln1_g + l * 1024, ln1_b + l * 1024, nullptr, X1B);
      gemm_bt<1, true, 1><<<dim3(64, 32, 1), dim3(256), 0, stream>>>(
          X1B, 1024, 0, 0, w1b, 1024, 0, 0, (void*)H1B, 4096, 0, 0,
          b1 + l * 4096, 1, 1024, 1.0f);
      gemm_bt<1, false, 0><<<dim3(64, 8, 1), dim3(256), 0, stream>>>(
          H1B, 4096, 0, 0, w2b, 4096, 0, 0, (void*)O32, 1024, 0, 0,
          b2 + l * 1024, 1, 4096, 1.0f);
      ln_kernel<true><<<dim3(8192), dim3(256), 0, stream>>>(
          X1B, O32, ln2_g + l * 1024, ln2_b + l * 1024, o32, o16);
    }
  };

  // upfront: gumbel bits + qkv/o weight casts for all 3 layers
  bbit_kernel<<<dim3(48), dim3(256), 0, stream>>>(alphas, gumE, bbit, 12288);
  cast_kernel<<<dim3(3072), dim3(256), 0, stream>>>(kW, kWb, 3145728);
  cast_kernel<<<dim3(3072), dim3(256), 0, stream>>>(vW, vWb, 3145728);
  cast_kernel<<<dim3(3072), dim3(256), 0, stream>>>(oW, oWb, 3145728);

  // layer 0: y = L0(qa, qa, qa), bmask=1, FFN. bf16(y) -> VB (layer2 values).
  cast_kernel<<<dim3(8192), dim3(256), 0, stream>>>(qa_emb, XB, ND);
  run_layer(0, qa_emb, false, XB, XB, true, 1, nullptr, VB);
  // layer 1: x = L1(q, q, q), bmask=1, no FFN. bf16(x) -> XB (layer2 q/k + residual).
  cast_kernel<<<dim3(8192), dim3(256), 0, stream>>>(q_emb, XB, ND);
  run_layer(1, q_emb, false, XB, XB, false, 1, nullptr, XB);
  // layer 2: out = L2(x, x, y), bmask=0 (zero_pad), FFN. residual read from bf16 XB.
  run_layer(2, XB, true, XB, VB, true, 0, outp, nullptr);
}